// Round 1
// baseline (1748.707 us; speedup 1.0000x reference)
//
#include <hip/hip_runtime.h>
#include <math.h>

#define B 16
#define CH 128
#define DIM 128
#define MODES 32
#define NLAYERS 4
#define PROJ 128
#define U 64            // stored kx modes: u<32 -> kx=u ; u>=32 -> kx=u+64 (96..127)
#define KY 32
#define NMODE (U*KY)    // 2048
#define N2 (DIM*DIM)    // 16384

// ---------------- K1: zf corners of rfft2(z), per batch ----------------
__global__ __launch_bounds__(256) void k_zf(const float* __restrict__ z,
                                            float* __restrict__ zfr, float* __restrict__ zfi) {
  __shared__ float zs[N2];                  // 64 KB
  __shared__ float twc[DIM], tws[DIM];      // 1 KB
  __shared__ float t1r[DIM][KY], t1i[DIM][KY]; // 32 KB
  int b = blockIdx.x, t = threadIdx.x;
  for (int idx = t * 4; idx < N2; idx += 256 * 4)
    *(float4*)&zs[idx] = *(const float4*)&z[b * N2 + idx];
  if (t < 128) {
    float ang = (float)(2.0 * M_PI) * (float)t / 128.0f;
    twc[t] = cosf(ang); tws[t] = sinf(ang);
  }
  __syncthreads();
  // phase 1: t1[x][ky] = sum_y z[x][y] e^{-2pi i ky y/128}
  for (int idx = t; idx < DIM * KY; idx += 256) {
    int x = idx >> 5, ky = idx & 31;
    float ar = 0.f, ai = 0.f;
    for (int y = 0; y < DIM; ++y) {
      float v = zs[x * DIM + y];
      int tt = (ky * y) & 127;
      ar += v * twc[tt];
      ai -= v * tws[tt];
    }
    t1r[x][ky] = ar; t1i[x][ky] = ai;
  }
  __syncthreads();
  // phase 2: zf[u][ky] = sum_x t1[x][ky] e^{-2pi i kx x/128}
  for (int idx = t; idx < U * KY; idx += 256) {
    int u = idx >> 5, ky = idx & 31;
    int kx = (u < 32) ? u : (u + 64);
    float ar = 0.f, ai = 0.f;
    for (int x = 0; x < DIM; ++x) {
      int tt = (kx * x) & 127;
      float c = twc[tt], s = tws[tt];
      float vr = t1r[x][ky], vi = t1i[x][ky];
      ar += vr * c + vi * s;
      ai += vi * c - vr * s;
    }
    zfr[b * NMODE + idx] = ar;
    zfi[b * NMODE + idx] = ai;
  }
}

// ---------------- K2: lift in spectral space ----------------
__global__ __launch_bounds__(256) void k_lift(const float* __restrict__ zfr, const float* __restrict__ zfi,
                                              const float* __restrict__ lw, const float* __restrict__ lb,
                                              float* __restrict__ vr, float* __restrict__ vi) {
  int idx = blockIdx.x * 256 + threadIdx.x;   // B*CH*NMODE = 4,194,304
  if (idx >= B * CH * NMODE) return;
  int m = idx & (NMODE - 1);
  int c = (idx >> 11) & 127;
  int b = idx >> 18;
  float w = lw[c];
  float re = w * zfr[b * NMODE + m];
  float im = w * zfi[b * NMODE + m];
  if (m == 0) re += 16384.f * lb[c];          // DC term of constant bias
  vr[idx] = re; vi[idx] = im;
}

// ---------------- K3: spectral einsum, one layer ----------------
// block = (u, o-tile of 16), XCD-swizzled so the 8 o-tiles of one u share an XCD L2.
__global__ __launch_bounds__(256) void k_spec(const float* __restrict__ vr, const float* __restrict__ vi,
                                              const float* __restrict__ wr1, const float* __restrict__ wi1,
                                              const float* __restrict__ wr2, const float* __restrict__ wi2,
                                              float* __restrict__ outr, float* __restrict__ outi) {
  int bid = blockIdx.x;
  int xcd = bid & 7, slot = bid >> 3;
  int u = (xcd << 3) | (slot & 7);
  int ot = slot >> 3;                       // 0..7
  int kxw = u & 31;
  const float* wr = (u >> 5) ? wr2 : wr1;
  const float* wi = (u >> 5) ? wi2 : wi1;
  int t = threadIdx.x;
  int ky = t & 31, bh = (t >> 5) & 1, q = t >> 6;   // q = wave id 0..3
  __shared__ float2 Vc[16][KY][17];         // [i_local][ky][b pad17] ~68 KB
  float accR[4][8] = {}, accI[4][8] = {};
  const int obase = ot * 16 + q * 4;
  for (int ic = 0; ic < CH; ic += 16) {
    __syncthreads();
    for (int e = t; e < 16 * 16 * KY; e += 256) {
      int kyy = e & 31;
      int bb = (e >> 5) & 15;
      int il = e >> 9;
      int g = ((bb * CH + (ic + il)) * U + u) * KY + kyy;
      Vc[il][kyy][bb] = make_float2(vr[g], vi[g]);
    }
    __syncthreads();
    for (int il = 0; il < 16; ++il) {
      int i = ic + il;
      float wrv[4], wiv[4];
      #pragma unroll
      for (int j = 0; j < 4; ++j) {
        int off = ((i * CH + obase + j) * MODES + kxw) * MODES + ky;
        wrv[j] = wr[off]; wiv[j] = wi[off];
      }
      float xr[8], xi[8];
      #pragma unroll
      for (int k = 0; k < 8; ++k) {
        float2 v = Vc[il][ky][bh * 8 + k];
        xr[k] = v.x; xi[k] = v.y;
      }
      #pragma unroll
      for (int j = 0; j < 4; ++j)
        #pragma unroll
        for (int k = 0; k < 8; ++k) {
          accR[j][k] += wrv[j] * xr[k] - wiv[j] * xi[k];
          accI[j][k] += wrv[j] * xi[k] + wiv[j] * xr[k];
        }
    }
  }
  #pragma unroll
  for (int j = 0; j < 4; ++j)
    #pragma unroll
    for (int k = 0; k < 8; ++k) {
      int o = obase + j, b = bh * 8 + k;
      int g = ((b * CH + o) * U + u) * KY + ky;
      outr[g] = accR[j][k]; outi[g] = accI[j][k];
    }
}

// ---------------- K3b: Hermitian projection of ky=0 column ----------------
// emulates the irfft2->rfft2 round trip between layers
__global__ __launch_bounds__(256) void k_proj0(float* __restrict__ re, float* __restrict__ im) {
  int idx = blockIdx.x * 256 + threadIdx.x;   // B*CH*33
  if (idx >= B * CH * 33) return;
  int pi = idx % 33;
  int bc = idx / 33;
  int base = bc * NMODE;
  if (pi == 0) {
    im[base] = 0.f;                           // kx=0: keep Re only
  } else if (pi == 32) {
    re[base + 32 * KY] *= 0.5f;               // kx=96: partner kx=32 is zero
    im[base + 32 * KY] *= 0.5f;
  } else {
    int ua = pi, ub = 64 - pi;                // kx and 128-kx
    float ar = re[base + ua * KY], ai = im[base + ua * KY];
    float br = re[base + ub * KY], bi = im[base + ub * KY];
    re[base + ua * KY] = 0.5f * (ar + br);
    im[base + ua * KY] = 0.5f * (ai - bi);
    re[base + ub * KY] = 0.5f * (br + ar);
    im[base + ub * KY] = 0.5f * (bi - ai);
  }
}

// ---------------- K4: pw1 applied in spectral space ----------------
__global__ __launch_bounds__(256) void k_pw1(const float* __restrict__ xr, const float* __restrict__ xi,
                                             const float* __restrict__ pw1,
                                             float* __restrict__ hr, float* __restrict__ hi) {
  __shared__ float wT[CH][CH];                // [c][p] 64 KB
  int bid = blockIdx.x;
  int b = bid >> 5, jt = bid & 31;            // jt: tile of 64 modes
  int t = threadIdx.x;
  for (int e = t; e < CH * CH; e += 256) {
    int p = e >> 7, c = e & 127;
    wT[c][p] = pw1[e];
  }
  __syncthreads();
  int tx = t & 15, ty = t >> 4;
  int j0 = jt * 64 + tx * 4;
  float accR[4][8] = {}, accI[4][8] = {};
  for (int c = 0; c < CH; ++c) {
    float4 r4 = *(const float4*)&xr[(b * CH + c) * NMODE + j0];
    float4 i4 = *(const float4*)&xi[(b * CH + c) * NMODE + j0];
    float w[8];
    #pragma unroll
    for (int pp = 0; pp < 8; ++pp) w[pp] = wT[c][ty * 8 + pp];
    float xrv[4] = {r4.x, r4.y, r4.z, r4.w};
    float xiv[4] = {i4.x, i4.y, i4.z, i4.w};
    #pragma unroll
    for (int jj = 0; jj < 4; ++jj)
      #pragma unroll
      for (int pp = 0; pp < 8; ++pp) {
        accR[jj][pp] += w[pp] * xrv[jj];
        accI[jj][pp] += w[pp] * xiv[jj];
      }
  }
  #pragma unroll
  for (int pp = 0; pp < 8; ++pp) {
    int p = ty * 8 + pp;
    float4 rr = make_float4(accR[0][pp], accR[1][pp], accR[2][pp], accR[3][pp]);
    float4 ii = make_float4(accI[0][pp], accI[1][pp], accI[2][pp], accI[3][pp]);
    *(float4*)&hr[(b * CH + p) * NMODE + j0] = rr;
    *(float4*)&hi[(b * CH + p) * NMODE + j0] = ii;
  }
}

// ---------------- K5: fused iDFT + bias + gelu(tanh) + pw2 ----------------
__global__ __launch_bounds__(256) void k_idft_proj(const float* __restrict__ hr, const float* __restrict__ hi,
                                                   const float* __restrict__ pb1, const float* __restrict__ pw2,
                                                   const float* __restrict__ pb2, float* __restrict__ outp) {
  __shared__ float Ct[KY][DIM], St[KY][DIM];  // 32 KB: wk*cos, -wk*sin tables
  __shared__ float twc[DIM], tws[DIM];
  __shared__ float hfr[U][KY], hfi[U][KY];    // 16 KB
  __shared__ float sr[KY][8], si[KY][8];      // s[ky][x]
  int bid = blockIdx.x;
  int b = bid >> 4, xs = bid & 15;            // 16 strips of 8 rows
  int x0 = xs * 8;
  int t = threadIdx.x;
  if (t < 128) {
    float ang = (float)(2.0 * M_PI) * (float)t / 128.0f;
    twc[t] = cosf(ang); tws[t] = sinf(ang);
  }
  __syncthreads();
  for (int e = t; e < KY * DIM; e += 256) {
    int ky = e >> 7, y = e & 127;
    int tt = (ky * y) & 127;
    float wk = (ky == 0) ? 1.f : 2.f;
    Ct[ky][y] = wk * twc[tt];
    St[ky][y] = -wk * tws[tt];
  }
  int xl = t >> 5, yb = (t & 31) * 4;         // pixel ownership for phase B
  float res[4] = {0.f, 0.f, 0.f, 0.f};
  float pb2v = pb2[0];
  __syncthreads();
  for (int p = 0; p < PROJ; ++p) {
    __syncthreads();
    for (int e = t; e < NMODE; e += 256)
      ((float*)hfr)[e] = hr[(b * CH + p) * NMODE + e];
    for (int e = t; e < NMODE; e += 256)
      ((float*)hfi)[e] = hi[(b * CH + p) * NMODE + e];
    __syncthreads();
    // phase A: s[ky][x] = sum_u hf[u][ky] e^{+2pi i kx x/128}
    {
      int ky = t & 31, xi_ = t >> 5;
      int x = x0 + xi_;
      float ar = 0.f, ai = 0.f;
      for (int uu = 0; uu < U; ++uu) {
        int kx = (uu < 32) ? uu : (uu + 64);
        int tt = (kx * x) & 127;
        float c = twc[tt], s = tws[tt];
        float r = hfr[uu][ky], i2 = hfi[uu][ky];
        ar += r * c - i2 * s;
        ai += r * s + i2 * c;
      }
      sr[ky][xi_] = ar; si[ky][xi_] = ai;
    }
    __syncthreads();
    // phase B: out[x][y] = (1/16384) sum_ky sr*C + si*S ; then gelu, pw2
    float acc[4] = {0.f, 0.f, 0.f, 0.f};
    for (int ky = 0; ky < KY; ++ky) {
      float r = sr[ky][xl], i2 = si[ky][xl];
      float4 c4 = *(float4*)&Ct[ky][yb];
      float4 s4 = *(float4*)&St[ky][yb];
      acc[0] += r * c4.x + i2 * s4.x;
      acc[1] += r * c4.y + i2 * s4.y;
      acc[2] += r * c4.z + i2 * s4.z;
      acc[3] += r * c4.w + i2 * s4.w;
    }
    float pw = pw2[p], pb = pb1[p];
    #pragma unroll
    for (int yy = 0; yy < 4; ++yy) {
      float h = acc[yy] * (1.f / 16384.f) + pb;
      float g = 0.5f * h * (1.f + tanhf(0.7978845608028654f * (h + 0.044715f * h * h * h)));
      res[yy] += pw * g;
    }
  }
  int x = x0 + xl;
  #pragma unroll
  for (int yy = 0; yy < 4; ++yy)
    outp[(b * DIM + x) * DIM + yb + yy] = res[yy] + pb2v;
}

extern "C" void kernel_launch(void* const* d_in, const int* in_sizes, int n_in,
                              void* d_out, int out_size, void* d_ws, size_t ws_size,
                              hipStream_t stream) {
  const float* z   = (const float*)d_in[0];
  const float* lw  = (const float*)d_in[1];
  const float* lb  = (const float*)d_in[2];
  const float* wr1 = (const float*)d_in[3];
  const float* wi1 = (const float*)d_in[4];
  const float* wr2 = (const float*)d_in[5];
  const float* wi2 = (const float*)d_in[6];
  const float* pw1 = (const float*)d_in[7];
  const float* pb1 = (const float*)d_in[8];
  const float* pw2 = (const float*)d_in[9];
  const float* pb2 = (const float*)d_in[10];
  float* out = (float*)d_out;
  float* ws = (float*)d_ws;

  // ws layout (floats): zf 2*32768, then two ping-pong complex buffers 4*4194304.
  // Total ~64.3 MB.
  float* zfr = ws;
  float* zfi = zfr + 32768;
  float* Ar  = zfi + 32768;
  float* Ai  = Ar + B * CH * NMODE;
  float* Br  = Ai + B * CH * NMODE;
  float* Bi  = Br + B * CH * NMODE;

  k_zf<<<B, 256, 0, stream>>>(z, zfr, zfi);
  k_lift<<<(B * CH * NMODE) / 256, 256, 0, stream>>>(zfr, zfi, lw, lb, Ar, Ai);

  const int WSTRIDE = CH * CH * MODES * MODES;
  float *ir = Ar, *ii = Ai, *orr = Br, *oi = Bi;
  for (int l = 0; l < NLAYERS; ++l) {
    k_spec<<<512, 256, 0, stream>>>(ir, ii,
                                    wr1 + (size_t)l * WSTRIDE, wi1 + (size_t)l * WSTRIDE,
                                    wr2 + (size_t)l * WSTRIDE, wi2 + (size_t)l * WSTRIDE,
                                    orr, oi);
    if (l < NLAYERS - 1)
      k_proj0<<<(B * CH * 33 + 255) / 256, 256, 0, stream>>>(orr, oi);
    float* tmp;
    tmp = ir; ir = orr; orr = tmp;
    tmp = ii; ii = oi;  oi = tmp;
  }
  // ir/ii = final spectral field; orr/oi free -> reuse for hf
  k_pw1<<<512, 256, 0, stream>>>(ir, ii, pw1, orr, oi);
  k_idft_proj<<<256, 256, 0, stream>>>(orr, oi, pb1, pw2, pb2, out);
}